// Round 18
// baseline (15.602 us; speedup 1.0000x reference)
//
#include <hip/hip_runtime.h>

#define N 2048
#define BS 16
#define QG 512             // queries per (b,qg) group: 8 per lane
#define NQG (N / QG)       // 4 query groups
#define QPL 8              // queries per lane
#define TS 128             // targets per slice
#define NTS (N / TS)       // 16 target slices
#define WAVES 4
#define TPB (WAVES * 64)   // 256 threads
#define TPW (TS / WAVES)   // 32 targets per wave
#define F4I (TPW / 4)      // 8 iterations of 4 targets

typedef float v2f __attribute__((ext_vector_type(2)));

// h = ng * x + h, packed over 2 targets (v_pk_fma_f32: 2 FMA/lane/inst).
#define PK_FMA(h, a, b) asm("v_pk_fma_f32 %0, %1, %2, %0" : "+v"(h) : "v"(a), "v"(b))

// R14-champion structure (1024 blocks x 256 thr, single dispatch) with
// QPL=8: per inner iteration 64 VALU : 4 ds_read_b128 (champion was 32:4),
// halving the LDS-issue share of the wave's serial issue stream. Total VALU
// work unchanged; grid geometry (the proven optimum) unchanged.
// Handoff (validated R12/R17): agent-scope atomic store/load for data;
// __syncthreads() drains vmcnt before counter bumps; atomicInc(p,K-1)
// poison-proof last-arrival election (elect old==K-2, steady-state across
// graph replays); NO __threadfence (L2 writeback storms, R11); NO
// per-element atomicMin (L3 RMW serialization, R16).
__global__ __launch_bounds__(TPB) void addsloss_fused(
    const float* __restrict__ target,
    const float* __restrict__ mp,
    const int* __restrict__ idx,
    const float* __restrict__ H,
    float* __restrict__ wsmin,
    float* __restrict__ partial,
    unsigned int* __restrict__ cnt2,
    unsigned int* __restrict__ cnt,
    float* __restrict__ out)
{
    __shared__ __align__(16) float xs[TS], ys[TS], zs[TS], ss[TS];  // 2 KB
    __shared__ float  pmin[WAVES][QG];   // 8 KB
    __shared__ float  ps[WAVES];
    __shared__ int    elect;

    const int bid  = blockIdx.x;
    const int b    = bid >> 6;        // / (NQG*NTS) = /64
    const int rem  = bid & 63;
    const int qg   = rem >> 4;        // / NTS
    const int ts   = rem & 15;        // % NTS
    const int tid  = threadIdx.x;
    const int wave = tid >> 6;
    const int lane = tid & 63;

    const int  cls = idx[b];
    const bool sym = (cls >= 0) && (cls <= 3);

    const float* tb = target + (size_t)b * N * 3;
    const float* mb = mp     + (size_t)b * N * 3;
    const float* hb = H      + b * 16;

    float d = 0.0f;   // this thread's summed per-query distances (2 queries)

    if (sym) {
        // ---- Phase 1: stage 128 targets SoA ----
        if (tid < TS) {
            const int t = ts * TS + tid;
            const float x = tb[t * 3 + 0];
            const float y = tb[t * 3 + 1];
            const float z = tb[t * 3 + 2];
            xs[tid] = x; ys[tid] = y; zs[tid] = z;
            ss[tid] = x * x + y * y + z * z;
        }

        // 8 queries per lane; broadcast -2*tf into packed pairs.
        v2f ngx[QPL], ngy[QPL], ngz[QPL];
        #pragma unroll
        for (int qi = 0; qi < QPL; ++qi) {
            const int q = qg * QG + qi * 64 + lane;
            const float m0 = mb[q * 3 + 0];
            const float m1 = mb[q * 3 + 1];
            const float m2 = mb[q * 3 + 2];
            const float gx = -2.0f * (hb[0] * m0 + hb[1]  * m1 + hb[2]  * m2 + hb[3]);
            const float gy = -2.0f * (hb[4] * m0 + hb[5]  * m1 + hb[6]  * m2 + hb[7]);
            const float gz = -2.0f * (hb[8] * m0 + hb[9]  * m1 + hb[10] * m2 + hb[11]);
            ngx[qi] = (v2f){gx, gx};
            ngy[qi] = (v2f){gy, gy};
            ngz[qi] = (v2f){gz, gz};
        }

        __syncthreads();

        // This wave scans targets [wave*32, wave*32+32), 4 per iteration;
        // each ds_read feeds 8 queries (64 VALU : 4 DS per iteration).
        const float4* x4 = reinterpret_cast<const float4*>(xs) + wave * F4I;
        const float4* y4 = reinterpret_cast<const float4*>(ys) + wave * F4I;
        const float4* z4 = reinterpret_cast<const float4*>(zs) + wave * F4I;
        const float4* s4 = reinterpret_cast<const float4*>(ss) + wave * F4I;

        float acc[QPL][2];
        #pragma unroll
        for (int qi = 0; qi < QPL; ++qi) { acc[qi][0] = 3.4e38f; acc[qi][1] = 3.4e38f; }

        #pragma unroll
        for (int j = 0; j < F4I; ++j) {
            const float4 X = x4[j], Y = y4[j], Z = z4[j], S = s4[j];
            const v2f Xlo = {X.x, X.y}, Xhi = {X.z, X.w};
            const v2f Ylo = {Y.x, Y.y}, Yhi = {Y.z, Y.w};
            const v2f Zlo = {Z.x, Z.y}, Zhi = {Z.z, Z.w};
            const v2f Slo = {S.x, S.y}, Shi = {S.z, S.w};
            #pragma unroll
            for (int qi = 0; qi < QPL; ++qi) {
                v2f h0 = Slo, h1 = Shi;
                PK_FMA(h0, ngx[qi], Xlo);
                PK_FMA(h1, ngx[qi], Xhi);
                PK_FMA(h0, ngy[qi], Ylo);
                PK_FMA(h1, ngy[qi], Yhi);
                PK_FMA(h0, ngz[qi], Zlo);
                PK_FMA(h1, ngz[qi], Zhi);
                acc[qi][0] = fminf(fminf(h0.x, h0.y), acc[qi][0]);  // v_min3
                acc[qi][1] = fminf(fminf(h1.x, h1.y), acc[qi][1]);
            }
        }

        #pragma unroll
        for (int qi = 0; qi < QPL; ++qi)
            pmin[wave][qi * 64 + lane] = fminf(acc[qi][0], acc[qi][1]);
        __syncthreads();

        // Publish this slice's per-query min, 2 per thread (agent-scope).
        #pragma unroll
        for (int k = 0; k < QG / TPB; ++k) {
            const int i = k * TPB + tid;
            const float m = fminf(fminf(pmin[0][i], pmin[1][i]),
                                  fminf(pmin[2][i], pmin[3][i]));
            __hip_atomic_store(&wsmin[((size_t)(b * NTS + ts)) * N + qg * QG + i],
                               m, __ATOMIC_RELAXED, __HIP_MEMORY_SCOPE_AGENT);
        }

        // ---- Election: last slice-block of this (b,qg) ----
        __syncthreads();   // s_waitcnt vmcnt(0) before barrier: publishes done
        if (tid == 0) {
            const unsigned int old = atomicInc(&cnt2[b * NQG + qg], NTS - 1);
            elect = (old == NTS - 2) ? 1 : 0;   // 16th (last) arrival
        }
        __syncthreads();
        if (!elect) return;

        // ---- Phase 2: 2 queries per thread ----
        #pragma unroll
        for (int k = 0; k < QG / TPB; ++k) {
            const int q = qg * QG + k * TPB + tid;
            float m = 3.4e38f;
            #pragma unroll
            for (int t = 0; t < NTS; ++t)
                m = fminf(m, __hip_atomic_load(&wsmin[((size_t)(b * NTS + t)) * N + q],
                                               __ATOMIC_RELAXED, __HIP_MEMORY_SCOPE_AGENT));
            const float m0 = mb[q * 3 + 0];
            const float m1 = mb[q * 3 + 1];
            const float m2 = mb[q * 3 + 2];
            const float fx = hb[0] * m0 + hb[1]  * m1 + hb[2]  * m2 + hb[3];
            const float fy = hb[4] * m0 + hb[5]  * m1 + hb[6]  * m2 + hb[7];
            const float fz = hb[8] * m0 + hb[9]  * m1 + hb[10] * m2 + hb[11];
            const float c = fx * fx + fy * fy + fz * fz;
            d += sqrtf(fmaxf(0.0f, c + m));
        }
    } else {
        if (ts != 0) return;   // one block per (b,qg) does the direct path
        #pragma unroll
        for (int k = 0; k < QG / TPB; ++k) {
            const int q = qg * QG + k * TPB + tid;
            const float m0 = mb[q * 3 + 0];
            const float m1 = mb[q * 3 + 1];
            const float m2 = mb[q * 3 + 2];
            const float fx = hb[0] * m0 + hb[1]  * m1 + hb[2]  * m2 + hb[3];
            const float fy = hb[4] * m0 + hb[5]  * m1 + hb[6]  * m2 + hb[7];
            const float fz = hb[8] * m0 + hb[9]  * m1 + hb[10] * m2 + hb[11];
            const float dx = fx - tb[q * 3 + 0];
            const float dy = fy - tb[q * 3 + 1];
            const float dz = fz - tb[q * 3 + 2];
            d += sqrtf(dx * dx + dy * dy + dz * dz);
        }
    }

    // ---- Fixed-order block sum of 512 distances -> partial[b][qg] ----
    #pragma unroll
    for (int off = 32; off > 0; off >>= 1) d += __shfl_down(d, off);
    if (lane == 0) ps[wave] = d;
    __syncthreads();
    if (tid == 0) {
        const float s = ps[0] + ps[1] + ps[2] + ps[3];
        __hip_atomic_store(&partial[b * NQG + qg], s,
                           __ATOMIC_RELAXED, __HIP_MEMORY_SCOPE_AGENT);
        // Ensure the partial store completed at L3 before bumping the counter.
        asm volatile("s_waitcnt vmcnt(0)" ::: "memory");
        const unsigned int old = atomicInc(&cnt[b], NQG - 1);
        if (old == NQG - 2) {               // 4th (last) group of this batch
            float tot = 0.0f;
            #pragma unroll
            for (int p = 0; p < NQG; ++p)
                tot += __hip_atomic_load(&partial[b * NQG + p],
                                         __ATOMIC_RELAXED, __HIP_MEMORY_SCOPE_AGENT);
            out[b] = tot * (1.0f / (float)N);
        }
    }
}

extern "C" void kernel_launch(void* const* d_in, const int* in_sizes, int n_in,
                              void* d_out, int out_size, void* d_ws, size_t ws_size,
                              hipStream_t stream) {
    const float* target = (const float*)d_in[0];   // [16, 2048, 3]
    const float* mp     = (const float*)d_in[1];   // [16, 2048, 3]
    const int*   idx    = (const int*)  d_in[2];   // [16, 1]
    const float* H      = (const float*)d_in[3];   // [16, 4, 4]
    float*       out    = (float*)d_out;           // [16]

    char* ws = (char*)d_ws;
    float*        wsmin   = (float*)ws;                              // 2 MB
    float*        partial = (float*)(ws + (size_t)BS * NTS * N * 4); // 64 f
    unsigned int* cnt2    = (unsigned int*)((char*)partial + 512);   // 64 u
    unsigned int* cnt     = (unsigned int*)((char*)cnt2 + 512);      // 16 u

    addsloss_fused<<<BS * NQG * NTS, TPB, 0, stream>>>(
        target, mp, idx, H, wsmin, partial, cnt2, cnt, out);
}

// Round 19
// 13.261 us; speedup vs baseline: 1.1765x; 1.1765x over previous
//
#include <hip/hip_runtime.h>

#define N 2048
#define BS 16
#define QG 256             // queries per (b,qg) group: 4 per lane
#define NQG (N / QG)       // 8 query groups
#define TS 256             // targets per slice
#define NTS (N / TS)       // 8 target slices
#define WAVES 4
#define TPB (WAVES * 64)   // 256 threads
#define TPW (TS / WAVES)   // 64 targets per wave
#define F4I (TPW / 4)      // 16 iterations of 4 targets

typedef float v2f __attribute__((ext_vector_type(2)));

// h = ng * x + h, packed over 2 targets (v_pk_fma_f32: 2 FMA/lane/inst).
#define PK_FMA(h, a, b) asm("v_pk_fma_f32 %0, %1, %2, %0" : "+v"(h) : "v"(a), "v"(b))

// R14 champion (13.4-13.9 us), final. Single dispatch, 1024 blocks x 256 thr.
// Inner loop: packed v_pk_fma_f32 over target pairs + v_min3 folds.
// Proven-out A/B ledger: QPL=4 optimal (QPL=8 regressed twice: R6, R18);
// 1024 blocks optimal (256 w/ 1024thr and 2048 both worse); agent-scope
// atomic store/load handoff (device coherence point, bypasses non-coherent
// XCD L2s); atomicInc(p,K-1) poison-proof last-arrival election (elect
// old==K-2, steady-state across graph replays); NO __threadfence (whole-L2
// writeback storms: 6x, R11); NO per-element atomicMin (L3 RMW serial., R16).
__global__ __launch_bounds__(TPB) void addsloss_fused(
    const float* __restrict__ target,
    const float* __restrict__ mp,
    const int* __restrict__ idx,
    const float* __restrict__ H,
    float* __restrict__ wsmin,
    float* __restrict__ partial,
    unsigned int* __restrict__ cnt2,
    unsigned int* __restrict__ cnt,
    float* __restrict__ out)
{
    __shared__ __align__(16) float xs[TS], ys[TS], zs[TS], ss[TS];  // 4 KB
    __shared__ float  pmin[WAVES][QG];   // 4 KB
    __shared__ float  ps[WAVES];
    __shared__ int    elect;

    const int bid  = blockIdx.x;
    const int b    = bid >> 6;        // / (NQG*NTS) = /64
    const int rem  = bid & 63;
    const int qg   = rem >> 3;        // / NTS
    const int ts   = rem & 7;         // % NTS
    const int tid  = threadIdx.x;
    const int wave = tid >> 6;
    const int lane = tid & 63;

    const int  cls = idx[b];
    const bool sym = (cls >= 0) && (cls <= 3);

    const float* tb = target + (size_t)b * N * 3;
    const float* mb = mp     + (size_t)b * N * 3;
    const float* hb = H      + b * 16;

    float d;   // this thread's final per-query distance (phase 2)

    if (sym) {
        // ---- Phase 1: stage 256 targets SoA, one per thread ----
        {
            const int t = ts * TS + tid;
            const float x = tb[t * 3 + 0];
            const float y = tb[t * 3 + 1];
            const float z = tb[t * 3 + 2];
            xs[tid] = x; ys[tid] = y; zs[tid] = z;
            ss[tid] = x * x + y * y + z * z;
        }

        // 4 queries per lane; broadcast -2*tf into packed pairs.
        v2f ngx[4], ngy[4], ngz[4];
        #pragma unroll
        for (int qi = 0; qi < 4; ++qi) {
            const int q = qg * QG + qi * 64 + lane;
            const float m0 = mb[q * 3 + 0];
            const float m1 = mb[q * 3 + 1];
            const float m2 = mb[q * 3 + 2];
            const float gx = -2.0f * (hb[0] * m0 + hb[1]  * m1 + hb[2]  * m2 + hb[3]);
            const float gy = -2.0f * (hb[4] * m0 + hb[5]  * m1 + hb[6]  * m2 + hb[7]);
            const float gz = -2.0f * (hb[8] * m0 + hb[9]  * m1 + hb[10] * m2 + hb[11]);
            ngx[qi] = (v2f){gx, gx};
            ngy[qi] = (v2f){gy, gy};
            ngz[qi] = (v2f){gz, gz};
        }

        __syncthreads();

        // This wave scans targets [wave*64, wave*64+64), 4 per iteration.
        const float4* x4 = reinterpret_cast<const float4*>(xs) + wave * F4I;
        const float4* y4 = reinterpret_cast<const float4*>(ys) + wave * F4I;
        const float4* z4 = reinterpret_cast<const float4*>(zs) + wave * F4I;
        const float4* s4 = reinterpret_cast<const float4*>(ss) + wave * F4I;

        float acc[4][2];
        #pragma unroll
        for (int qi = 0; qi < 4; ++qi) { acc[qi][0] = 3.4e38f; acc[qi][1] = 3.4e38f; }

        #pragma unroll 4
        for (int j = 0; j < F4I; ++j) {
            const float4 X = x4[j], Y = y4[j], Z = z4[j], S = s4[j];
            const v2f Xlo = {X.x, X.y}, Xhi = {X.z, X.w};
            const v2f Ylo = {Y.x, Y.y}, Yhi = {Y.z, Y.w};
            const v2f Zlo = {Z.x, Z.y}, Zhi = {Z.z, Z.w};
            const v2f Slo = {S.x, S.y}, Shi = {S.z, S.w};
            #pragma unroll
            for (int qi = 0; qi < 4; ++qi) {
                v2f h0 = Slo, h1 = Shi;
                PK_FMA(h0, ngx[qi], Xlo);
                PK_FMA(h1, ngx[qi], Xhi);
                PK_FMA(h0, ngy[qi], Ylo);
                PK_FMA(h1, ngy[qi], Yhi);
                PK_FMA(h0, ngz[qi], Zlo);
                PK_FMA(h1, ngz[qi], Zhi);
                acc[qi][0] = fminf(fminf(h0.x, h0.y), acc[qi][0]);  // v_min3
                acc[qi][1] = fminf(fminf(h1.x, h1.y), acc[qi][1]);
            }
        }

        #pragma unroll
        for (int qi = 0; qi < 4; ++qi)
            pmin[wave][qi * 64 + lane] = fminf(acc[qi][0], acc[qi][1]);
        __syncthreads();

        // Publish this slice's per-query min (agent-scope sc1 -> L3-coherent).
        {
            const float m = fminf(fminf(pmin[0][tid], pmin[1][tid]),
                                  fminf(pmin[2][tid], pmin[3][tid]));
            __hip_atomic_store(&wsmin[((size_t)(b * NTS + ts)) * N + qg * QG + tid],
                               m, __ATOMIC_RELAXED, __HIP_MEMORY_SCOPE_AGENT);
        }

        // ---- Election: last slice-block of this (b,qg) ----
        __syncthreads();   // s_waitcnt vmcnt(0) before barrier: publishes done
        if (tid == 0) {
            const unsigned int old = atomicInc(&cnt2[b * NQG + qg], NTS - 1);
            elect = (old == NTS - 2) ? 1 : 0;   // 8th (last) arrival
        }
        __syncthreads();
        if (!elect) return;

        // ---- Phase 2: q = qg*QG + tid ----
        const int q = qg * QG + tid;
        float m = 3.4e38f;
        #pragma unroll
        for (int t = 0; t < NTS; ++t)
            m = fminf(m, __hip_atomic_load(&wsmin[((size_t)(b * NTS + t)) * N + q],
                                           __ATOMIC_RELAXED, __HIP_MEMORY_SCOPE_AGENT));
        const float m0 = mb[q * 3 + 0];
        const float m1 = mb[q * 3 + 1];
        const float m2 = mb[q * 3 + 2];
        const float fx = hb[0] * m0 + hb[1]  * m1 + hb[2]  * m2 + hb[3];
        const float fy = hb[4] * m0 + hb[5]  * m1 + hb[6]  * m2 + hb[7];
        const float fz = hb[8] * m0 + hb[9]  * m1 + hb[10] * m2 + hb[11];
        const float c = fx * fx + fy * fy + fz * fz;
        d = sqrtf(fmaxf(0.0f, c + m));
    } else {
        if (ts != 0) return;   // one block per (b,qg) does the direct path
        const int q = qg * QG + tid;
        const float m0 = mb[q * 3 + 0];
        const float m1 = mb[q * 3 + 1];
        const float m2 = mb[q * 3 + 2];
        const float fx = hb[0] * m0 + hb[1]  * m1 + hb[2]  * m2 + hb[3];
        const float fy = hb[4] * m0 + hb[5]  * m1 + hb[6]  * m2 + hb[7];
        const float fz = hb[8] * m0 + hb[9]  * m1 + hb[10] * m2 + hb[11];
        const float dx = fx - tb[q * 3 + 0];
        const float dy = fy - tb[q * 3 + 1];
        const float dz = fz - tb[q * 3 + 2];
        d = sqrtf(dx * dx + dy * dy + dz * dz);
    }

    // ---- Fixed-order block sum of 256 distances -> partial[b][qg] ----
    #pragma unroll
    for (int off = 32; off > 0; off >>= 1) d += __shfl_down(d, off);
    if (lane == 0) ps[wave] = d;
    __syncthreads();
    if (tid == 0) {
        const float s = ps[0] + ps[1] + ps[2] + ps[3];
        __hip_atomic_store(&partial[b * NQG + qg], s,
                           __ATOMIC_RELAXED, __HIP_MEMORY_SCOPE_AGENT);
        // Ensure the partial store completed at L3 before bumping the counter.
        asm volatile("s_waitcnt vmcnt(0)" ::: "memory");
        const unsigned int old = atomicInc(&cnt[b], NQG - 1);
        if (old == NQG - 2) {               // 8th (last) group of this batch
            float tot = 0.0f;
            #pragma unroll
            for (int p = 0; p < NQG; ++p)
                tot += __hip_atomic_load(&partial[b * NQG + p],
                                         __ATOMIC_RELAXED, __HIP_MEMORY_SCOPE_AGENT);
            out[b] = tot * (1.0f / (float)N);
        }
    }
}

extern "C" void kernel_launch(void* const* d_in, const int* in_sizes, int n_in,
                              void* d_out, int out_size, void* d_ws, size_t ws_size,
                              hipStream_t stream) {
    const float* target = (const float*)d_in[0];   // [16, 2048, 3]
    const float* mp     = (const float*)d_in[1];   // [16, 2048, 3]
    const int*   idx    = (const int*)  d_in[2];   // [16, 1]
    const float* H      = (const float*)d_in[3];   // [16, 4, 4]
    float*       out    = (float*)d_out;           // [16]

    char* ws = (char*)d_ws;
    float*        wsmin   = (float*)ws;                              // 512 KB
    float*        partial = (float*)(ws + (size_t)BS * NTS * N * 4); // 128 f
    unsigned int* cnt2    = (unsigned int*)((char*)partial + 512);   // 128 u
    unsigned int* cnt     = (unsigned int*)((char*)cnt2 + 512);      // 16 u

    addsloss_fused<<<BS * NQG * NTS, TPB, 0, stream>>>(
        target, mp, idx, H, wsmin, partial, cnt2, cnt, out);
}